// Round 1
// baseline (458.845 us; speedup 1.0000x reference)
//
#include <hip/hip_runtime.h>

// DCT_Layer: fixed 4x4 2D-DCT grouped conv, padding=2, then min(|out|, 8).
// x: (8, 3, 512, 512) fp32  ->  out: (8, 48, 513, 513) fp32
//
// Key structure: DCT kernel is separable, k[kk*4+ll][i][j] = a[kk][i]*a[ll][j]
// with a[0]={.5,.5,.5,.5}, a[1]={A1,A2,-A2,-A1}, a[2]={.5,-.5,-.5,.5},
// a[3]={A2,-A1,A1,-A2}.  One thread per output pixel (b,c,oh,ow): load 4x4
// patch (predicated zero-pad), butterfly row+col transforms, 16 coalesced
// scalar store streams (row stride 513 floats => float4 stores would be
// misaligned, so scalar-per-plane is the right vector width here).

#define IHW 512
#define OHW 513

__global__ __launch_bounds__(256) void dct_layer_kernel(
    const float* __restrict__ x, float* __restrict__ out) {
    const float A1 = 0.6532814824381883f;   // sqrt(.5)*cos(pi/8)
    const float A2 = 0.2705980500730985f;   // sqrt(.5)*cos(3pi/8)

    int pix = blockIdx.x * 256 + threadIdx.x;          // oh*513 + ow
    if (pix >= OHW * OHW) return;
    int oh = pix / OHW;
    int ow = pix - oh * OHW;
    int bc = blockIdx.y;                               // b*3 + c, 0..23

    const float* __restrict__ xin = x + (size_t)bc * (IHW * IHW);

    // 4x4 input patch, zero outside [0,512)^2
    float p[4][4];
#pragma unroll
    for (int i = 0; i < 4; ++i) {
        int ih = oh - 2 + i;
        bool rv = ((unsigned)ih < (unsigned)IHW);
        const float* row = xin + ih * IHW;
#pragma unroll
        for (int j = 0; j < 4; ++j) {
            int iw = ow - 2 + j;
            bool ok = rv && ((unsigned)iw < (unsigned)IHW);
            p[i][j] = ok ? row[iw] : 0.0f;
        }
    }

    // vertical transform: t[kk][j] = sum_i a[kk][i] * p[i][j]  (butterfly)
    float t[4][4];
#pragma unroll
    for (int j = 0; j < 4; ++j) {
        float s03 = p[0][j] + p[3][j];
        float d03 = p[0][j] - p[3][j];
        float s12 = p[1][j] + p[2][j];
        float d12 = p[1][j] - p[2][j];
        t[0][j] = 0.5f * (s03 + s12);
        t[1][j] = A1 * d03 + A2 * d12;
        t[2][j] = 0.5f * (s03 - s12);
        t[3][j] = A2 * d03 - A1 * d12;
    }

    // horizontal transform: r[kk*4+ll] = sum_j a[ll][j] * t[kk][j]
    float r[16];
#pragma unroll
    for (int kk = 0; kk < 4; ++kk) {
        float s03 = t[kk][0] + t[kk][3];
        float d03 = t[kk][0] - t[kk][3];
        float s12 = t[kk][1] + t[kk][2];
        float d12 = t[kk][1] - t[kk][2];
        r[kk * 4 + 0] = 0.5f * (s03 + s12);
        r[kk * 4 + 1] = A1 * d03 + A2 * d12;
        r[kk * 4 + 2] = 0.5f * (s03 - s12);
        r[kk * 4 + 3] = A2 * d03 - A1 * d12;
    }

    // 16 output planes; lanes are consecutive in ow => each store coalesced
    const size_t PLANE = (size_t)OHW * OHW;
    size_t obase = (size_t)bc * 16 * PLANE + (size_t)pix;
#pragma unroll
    for (int c = 0; c < 16; ++c) {
        out[obase + (size_t)c * PLANE] = fminf(fabsf(r[c]), 8.0f);
    }
}

extern "C" void kernel_launch(void* const* d_in, const int* in_sizes, int n_in,
                              void* d_out, int out_size, void* d_ws, size_t ws_size,
                              hipStream_t stream) {
    const float* x = (const float*)d_in[0];
    float* out = (float*)d_out;
    dim3 grid((OHW * OHW + 255) / 256, 24);  // 1029 x 24 blocks
    hipLaunchKernelGGL(dct_layer_kernel, grid, dim3(256), 0, stream, x, out);
}